// Round 7
// baseline (111.355 us; speedup 1.0000x reference)
//
#include <hip/hip_runtime.h>
#include <stdint.h>

#define B_   32
#define CIN  128
#define HH   56
#define WW   56
#define COUT 256
#define QDIV 7.5f

#define NBLK_AX 2048
#define NBLK_AW 288
#define NBLK_QX (B_ * HH)   // 1792
#define NBLK_QW 288

#define NSLOT 66
#define CSTRIDE (NSLOT * 16)       // 1056 B per ci-chunk
#define ROWB (8 * CSTRIDE)         // 8448 B per image row
#define XROWS 10
#define XLDS_BYTES (XROWS * ROWB)  // 84480
#define WHALF 36864                // 18 chunks * 2048 B
#define LDS_TOTAL (XLDS_BYTES + WHALF)  // 121344
#define WGRP 73728                 // 72 KB of weights per 64-co group

typedef int v4i  __attribute__((ext_vector_type(4)));
typedef int v16i __attribute__((ext_vector_type(16)));

typedef __attribute__((address_space(3))) unsigned char lds_u8;
typedef __attribute__((address_space(1))) const unsigned char glb_u8;

__device__ __forceinline__ void load_lds16(const void* g, void* l) {
    __builtin_amdgcn_global_load_lds((glb_u8*)g, (lds_u8*)l, 16, 0, 0);
}

// ---------- absmax: blocks [0,2048) -> x, [2048,2336) -> w ----------
__global__ __launch_bounds__(256) void absmax_all_kernel(const float* __restrict__ x,
                                                         const float* __restrict__ w,
                                                         unsigned* __restrict__ mbits) {
    const float* p; int n4, i, stride; unsigned* slot;
    if (blockIdx.x < NBLK_AX) {
        p = x; n4 = B_ * CIN * HH * WW / 4;
        i = blockIdx.x * 256 + threadIdx.x; stride = NBLK_AX * 256; slot = mbits;
    } else {
        p = w; n4 = COUT * CIN * 9 / 4;
        i = (blockIdx.x - NBLK_AX) * 256 + threadIdx.x; stride = NBLK_AW * 256; slot = mbits + 1;
    }
    float m = 0.f;
    for (; i < n4; i += stride) {
        float4 v = ((const float4*)p)[i];
        m = fmaxf(m, fmaxf(fmaxf(fabsf(v.x), fabsf(v.y)),
                           fmaxf(fabsf(v.z), fabsf(v.w))));
    }
    #pragma unroll
    for (int off = 32; off; off >>= 1) m = fmaxf(m, __shfl_down(m, off));
    __shared__ float red[4];
    int lane = threadIdx.x & 63, wv = threadIdx.x >> 6;
    if (lane == 0) red[wv] = m;
    __syncthreads();
    if (threadIdx.x == 0) {
        m = fmaxf(fmaxf(red[0], red[1]), fmaxf(red[2], red[3]));
        atomicMax(slot, __float_as_uint(m));
    }
}

// ---------- quantize: blocks [0,1792) -> x, [1792,2080) -> w ----------
// qx (chunk-major, zero border baked): per (b,h) row of 8448 B:
//   byte addr = c*1056 + s*16 + j ; slot s in [1,56] = pixel w=s-1, ci = c*16+j
// qw3: byte addr = g*73728 + k*2048 + mi*1024 + jh*512 + co31*16 + jl
//   where co = g*64 + mi*32 + co31, k = (kh*3+kw)*4 + cc, k-byte j = jh*16+jl,
//   ci = cc*32 + j.  A-fragment(k,mi) = chunkbase + mi*1024 + lane*16.
__global__ __launch_bounds__(256) void quant_all_kernel(const float* __restrict__ x,
                                                        const float* __restrict__ w,
                                                        signed char* __restrict__ qx,
                                                        int* __restrict__ qw,
                                                        const unsigned* __restrict__ mbits) {
    if (blockIdx.x < NBLK_QX) {
        __shared__ signed char tile[WW * 132];
        const int bh = blockIdx.x;
        const int b = bh / HH, h = bh % HH;
        const float s = __uint_as_float(mbits[0]) / QDIV;
        const float* src = x + (size_t)b * (CIN * HH * WW) + (size_t)h * WW;
        for (int e = threadIdx.x; e < CIN * WW; e += 256) {
            int ci = e / WW, ww = e - ci * WW;
            float v = src[(size_t)ci * (HH * WW) + ww];
            float q = fminf(fmaxf(rintf(v / s), -8.f), 7.f);
            tile[ww * 132 + ci] = (signed char)q;
        }
        __syncthreads();
        int* dst = (int*)(qx + (size_t)bh * ROWB);
        for (int d = threadIdx.x; d < ROWB / 4; d += 256) {   // 2112 dwords
            int u = d >> 2, dw = d & 3;
            int c = u / NSLOT, s2 = u - c * NSLOT;
            int v = 0;
            if (s2 >= 1 && s2 <= WW)
                v = *(const int*)&tile[(s2 - 1) * 132 + c * 16 + dw * 4];
            dst[d] = v;
        }
    } else {
        int d = (blockIdx.x - NBLK_QX) * 256 + threadIdx.x;  // 73728 dwords
        int g  = d / 18432;
        int r1 = d - g * 18432;
        int k  = r1 >> 9;
        int q9 = r1 & 511;
        int mi = q9 >> 8;
        int u2 = q9 & 255;
        int jh = u2 >> 7;
        int co31 = (u2 >> 2) & 31;
        int jl4  = u2 & 3;
        int co = g * 64 + mi * 32 + co31;
        int t = k >> 2, cc = k & 3;
        int kh = t / 3, kw = t - kh * 3;
        float s = __uint_as_float(mbits[1]) / QDIV;
        int pack = 0;
        #pragma unroll
        for (int j = 0; j < 4; ++j) {
            int ci = cc * 32 + jh * 16 + jl4 * 4 + j;
            float v = w[(((size_t)co * CIN + ci) * 3 + kh) * 3 + kw];
            float q = fminf(fmaxf(rintf(v / s), -8.f), 7.f);
            pack |= (((int)q) & 0xFF) << (8 * j);
        }
        qw[d] = pack;
    }
}

// ---------- conv: i8-MFMA, everything staged BEFORE the K-loop ----------
// Block: 512 thr / 8 waves; 64 co (group g) x 8 output rows; wave = 64co x 56px,
// acc[2][2]. LDS: x rows h0-1..h0+8 (84.5 KB) + 18-chunk weight half (36 KB).
// K-loop: pure ds_read+MFMA, no barriers, no staging; one mid-loop restage
// swaps in the second K-half.
__global__ __launch_bounds__(512, 2) void conv_mfma_kernel(
        const signed char* __restrict__ qx,
        const signed char* __restrict__ qxzero,
        const signed char* __restrict__ qw3,
        const unsigned* __restrict__ mbits,
        const float* __restrict__ bias,
        float* __restrict__ out) {
    __shared__ signed char lds[LDS_TOTAL];
    signed char* xlds = lds;
    signed char* wlds = lds + XLDS_BYTES;

    // XCD-chunked swizzle (896 % 8 == 0 -> bijective); g fastest within a chunk
    const int sw  = (blockIdx.x & 7) * 112 + (blockIdx.x >> 3);
    const int g   = sw & 3;
    const int brg = sw >> 2;          // 0..223
    const int rg  = brg % 7;
    const int b   = brg / 7;
    const int h0  = rg * 8;

    const int tid    = threadIdx.x;
    const int rowidx = tid >> 6;      // wave id = output row 0..7
    const int lane   = tid & 63;
    const int l31    = tid & 31;
    const int lhalf  = (tid >> 5) & 1;

    // ---- prologue: stage x rows h0-1..h0+8 (5280 16B units) + weight half 0 ----
    const signed char* qxb = qx + (size_t)(b * HH) * ROWB;
    #pragma unroll
    for (int i = 0; i < 10; ++i) {
        const int u = tid + i * 512;
        const int r = u / 528, c = u - r * 528;
        const int hy = h0 - 1 + r;
        const signed char* src = (hy >= 0 && hy < HH) ? qxb + hy * ROWB + c * 16
                                                      : qxzero + c * 16;
        load_lds16(src, xlds + u * 16);
    }
    if (tid < 160) {
        const int u = 5120 + tid;
        const int r = u / 528, c = u - r * 528;
        const int hy = h0 - 1 + r;
        const signed char* src = (hy < HH) ? qxb + hy * ROWB + c * 16
                                           : qxzero + c * 16;
        load_lds16(src, xlds + u * 16);
    }
    {
        const signed char* ws0 = qw3 + g * WGRP;
        #pragma unroll
        for (int i = 0; i < 4; ++i)
            load_lds16(ws0 + (tid + i * 512) * 16, wlds + (tid + i * 512) * 16);
        if (tid < 256)
            load_lds16(ws0 + (2048 + tid) * 16, wlds + (2048 + tid) * 16);
    }
    __syncthreads();

    v16i acc[2][2];
    #pragma unroll
    for (int mi = 0; mi < 2; ++mi)
        #pragma unroll
        for (int ni = 0; ni < 2; ++ni)
            #pragma unroll
            for (int r = 0; r < 16; ++r) acc[mi][ni][r] = 0;

#define KSTEP(K, K2)                                                                        \
    {                                                                                       \
        const int t_ = (K) >> 2, cc_ = (K) & 3;                                             \
        const int kh_ = t_ / 3, kw_ = t_ - kh_ * 3;                                         \
        const signed char* ap_ = wlds + (K2) * 2048 + lane * 16;                            \
        const v4i a0_ = *(const v4i*)ap_;                                                   \
        const v4i a1_ = *(const v4i*)(ap_ + 1024);                                          \
        const signed char* xp_ = xlds + (rowidx + kh_) * ROWB                               \
                                 + (cc_ * 2 + lhalf) * CSTRIDE + (l31 + kw_) * 16;          \
        const v4i b0_ = *(const v4i*)xp_;                                                   \
        const v4i b1_ = *(const v4i*)(xp_ + 512);                                           \
        acc[0][0] = __builtin_amdgcn_mfma_i32_32x32x32_i8(a0_, b0_, acc[0][0], 0, 0, 0);    \
        acc[1][0] = __builtin_amdgcn_mfma_i32_32x32x32_i8(a1_, b0_, acc[1][0], 0, 0, 0);    \
        acc[0][1] = __builtin_amdgcn_mfma_i32_32x32x32_i8(a0_, b1_, acc[0][1], 0, 0, 0);    \
        acc[1][1] = __builtin_amdgcn_mfma_i32_32x32x32_i8(a1_, b1_, acc[1][1], 0, 0, 0);    \
    }

    #pragma unroll
    for (int k2 = 0; k2 < 18; ++k2) KSTEP(k2, k2)

    // ---- swap in second K-half ----
    __syncthreads();
    {
        const signed char* ws1 = qw3 + g * WGRP + WHALF;
        #pragma unroll
        for (int i = 0; i < 4; ++i)
            load_lds16(ws1 + (tid + i * 512) * 16, wlds + (tid + i * 512) * 16);
        if (tid < 256)
            load_lds16(ws1 + (2048 + tid) * 16, wlds + (2048 + tid) * 16);
    }
    __syncthreads();

    #pragma unroll
    for (int k2 = 0; k2 < 18; ++k2) KSTEP(k2 + 18, k2)
#undef KSTEP

    // ---- epilogue: dequant + bias ----
    const float s = (__uint_as_float(mbits[0]) / QDIV) *
                    (__uint_as_float(mbits[1]) / QDIV);
    const int hrow = h0 + rowidx;
    #pragma unroll
    for (int mi = 0; mi < 2; ++mi) {
        #pragma unroll
        for (int r = 0; r < 16; ++r) {
            const int co = g * 64 + mi * 32 + (r & 3) + 8 * (r >> 2) + 4 * lhalf;
            const float bv = bias[co];
            float* orow = out + ((size_t)(b * COUT + co) * HH + hrow) * WW;
            orow[l31] = (float)acc[mi][0][r] * s + bv;
            if (l31 < WW - 32) orow[32 + l31] = (float)acc[mi][1][r] * s + bv;
        }
    }
}

extern "C" void kernel_launch(void* const* d_in, const int* in_sizes, int n_in,
                              void* d_out, int out_size, void* d_ws, size_t ws_size,
                              hipStream_t stream) {
    const float* x    = (const float*)d_in[0];
    const float* w    = (const float*)d_in[1];
    const float* bias = (const float*)d_in[2];
    float* out = (float*)d_out;

    unsigned* mbits = (unsigned*)d_ws;
    signed char* qx     = (signed char*)d_ws + 256;
    signed char* qxzero = qx + (size_t)B_ * HH * ROWB;
    signed char* qw3    = qxzero + ROWB;

    hipMemsetAsync(d_ws, 0, 8, stream);
    hipMemsetAsync(qxzero, 0, ROWB, stream);
    hipLaunchKernelGGL(absmax_all_kernel, dim3(NBLK_AX + NBLK_AW), dim3(256), 0, stream,
                       x, w, mbits);
    hipLaunchKernelGGL(quant_all_kernel, dim3(NBLK_QX + NBLK_QW), dim3(256), 0, stream,
                       x, w, qx, (int*)qw3, mbits);
    hipLaunchKernelGGL(conv_mfma_kernel, dim3(B_ * 7 * 4), dim3(512), 0, stream,
                       qx, qxzero, qw3, mbits, bias, out);
}

// Round 8
// 107.220 us; speedup vs baseline: 1.0386x; 1.0386x over previous
//
#include <hip/hip_runtime.h>
#include <stdint.h>

#define B_   32
#define CIN  128
#define HH   56
#define WW   56
#define COUT 256
#define QDIV 7.5f

#define NBLK_AX 2048
#define NBLK_AW 288
#define NBLK_QX (B_ * HH)   // 1792
#define NBLK_QW 288

#define NSLOT 58
#define CSTRIDE (NSLOT * 16)       // 928 B per ci-chunk
#define ROWB (8 * CSTRIDE)         // 7424 B per image row
#define XROWS 6
#define XLDS_BYTES (XROWS * ROWB)  // 44544
#define WSEG 18432                 // 9 chunks * 2048 B
#define LDS_TOTAL (XLDS_BYTES + 2 * WSEG)  // 81408 -> 2 blocks/CU
#define WGRP 73728                 // 72 KB weights per 64-co group

typedef int v4i  __attribute__((ext_vector_type(4)));
typedef int v16i __attribute__((ext_vector_type(16)));

typedef __attribute__((address_space(3))) unsigned char lds_u8;
typedef __attribute__((address_space(1))) const unsigned char glb_u8;

__device__ __forceinline__ void load_lds16(const void* g, void* l) {
    __builtin_amdgcn_global_load_lds((glb_u8*)g, (lds_u8*)l, 16, 0, 0);
}

// ---------- absmax: blocks [0,2048) -> x, [2048,2336) -> w ----------
__global__ __launch_bounds__(256) void absmax_all_kernel(const float* __restrict__ x,
                                                         const float* __restrict__ w,
                                                         unsigned* __restrict__ mbits) {
    const float* p; int n4, i, stride; unsigned* slot;
    if (blockIdx.x < NBLK_AX) {
        p = x; n4 = B_ * CIN * HH * WW / 4;
        i = blockIdx.x * 256 + threadIdx.x; stride = NBLK_AX * 256; slot = mbits;
    } else {
        p = w; n4 = COUT * CIN * 9 / 4;
        i = (blockIdx.x - NBLK_AX) * 256 + threadIdx.x; stride = NBLK_AW * 256; slot = mbits + 1;
    }
    float m = 0.f;
    for (; i < n4; i += stride) {
        float4 v = ((const float4*)p)[i];
        m = fmaxf(m, fmaxf(fmaxf(fabsf(v.x), fabsf(v.y)),
                           fmaxf(fabsf(v.z), fabsf(v.w))));
    }
    #pragma unroll
    for (int off = 32; off; off >>= 1) m = fmaxf(m, __shfl_down(m, off));
    __shared__ float red[4];
    int lane = threadIdx.x & 63, wv = threadIdx.x >> 6;
    if (lane == 0) red[wv] = m;
    __syncthreads();
    if (threadIdx.x == 0) {
        m = fmaxf(fmaxf(red[0], red[1]), fmaxf(red[2], red[3]));
        atomicMax(slot, __float_as_uint(m));
    }
}

// ---------- quantize: blocks [0,1792) -> x, [1792,2080) -> w ----------
// qx: per (b,h) row of 7424 B: byte = c*928 + s*16 + j; slot s in [1,56] holds
//     pixel w = s-1, ci = c*16+j; slots 0 and 57 zero.
// qw3: byte = g*73728 + k*2048 + mi*1024 + jh*512 + co31*16 + jl
//   co = g*64 + mi*32 + co31, k = (kh*3+kw)*4 + cc, ci = cc*32 + jh*16 + jl.
__global__ __launch_bounds__(256) void quant_all_kernel(const float* __restrict__ x,
                                                        const float* __restrict__ w,
                                                        signed char* __restrict__ qx,
                                                        int* __restrict__ qw,
                                                        const unsigned* __restrict__ mbits) {
    if (blockIdx.x < NBLK_QX) {
        __shared__ signed char tile[WW * 132];
        const int bh = blockIdx.x;
        const int b = bh / HH, h = bh % HH;
        const float s = __uint_as_float(mbits[0]) / QDIV;
        const float* src = x + (size_t)b * (CIN * HH * WW) + (size_t)h * WW;
        for (int e = threadIdx.x; e < CIN * WW; e += 256) {
            int ci = e / WW, ww = e - ci * WW;
            float v = src[(size_t)ci * (HH * WW) + ww];
            float q = fminf(fmaxf(rintf(v / s), -8.f), 7.f);
            tile[ww * 132 + ci] = (signed char)q;
        }
        __syncthreads();
        int* dst = (int*)(qx + (size_t)bh * ROWB);
        for (int d = threadIdx.x; d < ROWB / 4; d += 256) {   // 1856 dwords
            int u = d >> 2, dw = d & 3;
            int c = u / NSLOT, s2 = u - c * NSLOT;
            int v = 0;
            if (s2 >= 1 && s2 <= WW)
                v = *(const int*)&tile[(s2 - 1) * 132 + c * 16 + dw * 4];
            dst[d] = v;
        }
    } else {
        int d = (blockIdx.x - NBLK_QX) * 256 + threadIdx.x;  // 73728 dwords
        int g  = d / 18432;
        int r1 = d - g * 18432;
        int k  = r1 >> 9;
        int q9 = r1 & 511;
        int mi = q9 >> 8;
        int u2 = q9 & 255;
        int jh = u2 >> 7;
        int co31 = (u2 >> 2) & 31;
        int jl4  = u2 & 3;
        int co = g * 64 + mi * 32 + co31;
        int t = k >> 2, cc = k & 3;
        int kh = t / 3, kw = t - kh * 3;
        float s = __uint_as_float(mbits[1]) / QDIV;
        int pack = 0;
        #pragma unroll
        for (int j = 0; j < 4; ++j) {
            int ci = cc * 32 + jh * 16 + jl4 * 4 + j;
            float v = w[(((size_t)co * CIN + ci) * 3 + kh) * 3 + kw];
            float q = fminf(fmaxf(rintf(v / s), -8.f), 7.f);
            pack |= (((int)q) & 0xFF) << (8 * j);
        }
        qw[d] = pack;
    }
}

// ---------- conv: i8-MFMA, 2 blocks/CU, segment-double-buffered weights ----------
// Block: 256 thr / 4 waves; 64 co (group g) x 4 output rows; wave = 64co x 56px,
// acc[2][2]. LDS: x rows h0-1..h0+4 (44.5 KB) + weight dbuf 2x18KB = 81.4 KB
// -> 2 blocks/CU. K-loop: 4 segments x 9 pure ds_read+MFMA steps; next segment
// staged during compute; one barrier per segment.
__global__ __launch_bounds__(256, 2) void conv_mfma_kernel(
        const signed char* __restrict__ qx,
        const signed char* __restrict__ qxzero,
        const signed char* __restrict__ qw3,
        const unsigned* __restrict__ mbits,
        const float* __restrict__ bias,
        float* __restrict__ out) {
    __shared__ signed char lds[LDS_TOTAL];
    signed char* xlds = lds;
    signed char* wlds = lds + XLDS_BYTES;

    // XCD-chunked swizzle (1792 % 8 == 0 -> bijective); g fastest in a chunk
    const int sbid = (blockIdx.x & 7) * 224 + (blockIdx.x >> 3);
    const int g    = sbid & 3;
    const int brg  = sbid >> 2;       // 0..447
    const int rg   = brg % 14;
    const int b    = brg / 14;
    const int h0   = rg * 4;

    const int tid    = threadIdx.x;
    const int rowidx = tid >> 6;      // wave id = output row 0..3
    const int lane   = tid & 63;
    const int l31    = tid & 31;
    const int lhalf  = (tid >> 5) & 1;

    // ---- prologue: weight segment 0 + x rows h0-1..h0+4 (2784 16B units) ----
    {
        const signed char* ws0 = qw3 + g * WGRP;
        #pragma unroll
        for (int i = 0; i < 5; ++i) {
            const int u = tid + i * 256;
            if (u < 1152) load_lds16(ws0 + u * 16, wlds + u * 16);
        }
    }
    const signed char* qxb = qx + (size_t)(b * HH) * ROWB;
    #pragma unroll
    for (int i = 0; i < 11; ++i) {
        const int u = tid + i * 256;
        if (u < 2784) {
            const int r = u / 464, c = u - r * 464;
            const int hy = h0 - 1 + r;
            const signed char* src = (hy >= 0 && hy < HH) ? qxb + hy * ROWB + c * 16
                                                          : qxzero + c * 16;
            load_lds16(src, xlds + u * 16);
        }
    }
    __syncthreads();

    v16i acc[2][2];
    #pragma unroll
    for (int mi = 0; mi < 2; ++mi)
        #pragma unroll
        for (int ni = 0; ni < 2; ++ni)
            #pragma unroll
            for (int r = 0; r < 16; ++r) acc[mi][ni][r] = 0;

    #pragma unroll
    for (int s = 0; s < 4; ++s) {
        if (s < 3) {   // stage next segment into the other buffer
            const signed char* gsrc = qw3 + g * WGRP + (s + 1) * WSEG;
            signed char* ldst = wlds + ((s + 1) & 1) * WSEG;
            #pragma unroll
            for (int i = 0; i < 5; ++i) {
                const int u = tid + i * 256;
                if (u < 1152) load_lds16(gsrc + u * 16, ldst + u * 16);
            }
        }
        const signed char* wseg = wlds + (s & 1) * WSEG;
        #pragma unroll
        for (int j = 0; j < 9; ++j) {
            const int K = s * 9 + j;
            const int t = K >> 2, cc = K & 3;
            const int kh = t / 3, kw = t - kh * 3;
            const signed char* ap = wseg + j * 2048 + lane * 16;
            const v4i a0 = *(const v4i*)ap;
            const v4i a1 = *(const v4i*)(ap + 1024);
            const signed char* xp = xlds + (rowidx + kh) * ROWB
                                    + (cc * 2 + lhalf) * CSTRIDE + (l31 + kw) * 16;
            const v4i b0 = *(const v4i*)xp;
            const v4i b1 = *(const v4i*)(xp + 512);
            __builtin_amdgcn_s_setprio(1);
            acc[0][0] = __builtin_amdgcn_mfma_i32_32x32x32_i8(a0, b0, acc[0][0], 0, 0, 0);
            acc[1][0] = __builtin_amdgcn_mfma_i32_32x32x32_i8(a1, b0, acc[1][0], 0, 0, 0);
            acc[0][1] = __builtin_amdgcn_mfma_i32_32x32x32_i8(a0, b1, acc[0][1], 0, 0, 0);
            acc[1][1] = __builtin_amdgcn_mfma_i32_32x32x32_i8(a1, b1, acc[1][1], 0, 0, 0);
            __builtin_amdgcn_s_setprio(0);
        }
        if (s < 3) __syncthreads();   // publish next buffer (drains staging)
    }

    // ---- epilogue: dequant + bias ----
    const float s = (__uint_as_float(mbits[0]) / QDIV) *
                    (__uint_as_float(mbits[1]) / QDIV);
    const int hrow = h0 + rowidx;
    #pragma unroll
    for (int mi = 0; mi < 2; ++mi) {
        #pragma unroll
        for (int r = 0; r < 16; ++r) {
            const int co = g * 64 + mi * 32 + (r & 3) + 8 * (r >> 2) + 4 * lhalf;
            const float bv = bias[co];
            float* orow = out + ((size_t)(b * COUT + co) * HH + hrow) * WW;
            orow[l31] = (float)acc[mi][0][r] * s + bv;
            if (l31 < WW - 32) orow[32 + l31] = (float)acc[mi][1][r] * s + bv;
        }
    }
}

extern "C" void kernel_launch(void* const* d_in, const int* in_sizes, int n_in,
                              void* d_out, int out_size, void* d_ws, size_t ws_size,
                              hipStream_t stream) {
    const float* x    = (const float*)d_in[0];
    const float* w    = (const float*)d_in[1];
    const float* bias = (const float*)d_in[2];
    float* out = (float*)d_out;

    unsigned* mbits = (unsigned*)d_ws;
    signed char* qxzero = (signed char*)d_ws + 256;
    signed char* qx     = qxzero + ROWB;
    signed char* qw3    = qx + (size_t)B_ * HH * ROWB;

    hipMemsetAsync(d_ws, 0, 256 + ROWB, stream);   // mbits + qxzero in one shot
    hipLaunchKernelGGL(absmax_all_kernel, dim3(NBLK_AX + NBLK_AW), dim3(256), 0, stream,
                       x, w, mbits);
    hipLaunchKernelGGL(quant_all_kernel, dim3(NBLK_QX + NBLK_QW), dim3(256), 0, stream,
                       x, w, qx, (int*)qw3, mbits);
    hipLaunchKernelGGL(conv_mfma_kernel, dim3(B_ * 14 * 4), dim3(256), 0, stream,
                       qx, qxzero, qw3, mbits, bias, out);
}

// Round 9
// 101.827 us; speedup vs baseline: 1.0936x; 1.0530x over previous
//
#include <hip/hip_runtime.h>
#include <stdint.h>

#define B_   32
#define CIN  128
#define HH   56
#define WW   56
#define COUT 256
#define QDIV 7.5f

#define NBLK_AX 2048
#define NBLK_AW 288
#define NBLK_QX (B_ * HH)   // 1792
#define NBLK_QW 288

#define NSLOT 58
#define CSTRIDE (NSLOT * 16)       // 928 B per ci-chunk
#define ROWB (8 * CSTRIDE)         // 7424 B per image row
#define XROWS 6
#define XLDS_BYTES (XROWS * ROWB)  // 44544
#define WSEG 4096                  // 2 chunks * 2048 B
#define LDS_TOTAL (XLDS_BYTES + 2 * WSEG)  // 52736 -> 3 blocks/CU
#define WGRP 73728                 // 72 KB weights per 64-co group

typedef int v4i  __attribute__((ext_vector_type(4)));
typedef int v16i __attribute__((ext_vector_type(16)));

typedef __attribute__((address_space(3))) unsigned char lds_u8;
typedef __attribute__((address_space(1))) const unsigned char glb_u8;

__device__ __forceinline__ void load_lds16(const void* g, void* l) {
    __builtin_amdgcn_global_load_lds((glb_u8*)g, (lds_u8*)l, 16, 0, 0);
}

// ---------- absmax: blocks [0,2048) -> x, [2048,2336) -> w ----------
__global__ __launch_bounds__(256) void absmax_all_kernel(const float* __restrict__ x,
                                                         const float* __restrict__ w,
                                                         unsigned* __restrict__ mbits) {
    const float* p; int n4, i, stride; unsigned* slot;
    if (blockIdx.x < NBLK_AX) {
        p = x; n4 = B_ * CIN * HH * WW / 4;
        i = blockIdx.x * 256 + threadIdx.x; stride = NBLK_AX * 256; slot = mbits;
    } else {
        p = w; n4 = COUT * CIN * 9 / 4;
        i = (blockIdx.x - NBLK_AX) * 256 + threadIdx.x; stride = NBLK_AW * 256; slot = mbits + 1;
    }
    float m = 0.f;
    for (; i < n4; i += stride) {
        float4 v = ((const float4*)p)[i];
        m = fmaxf(m, fmaxf(fmaxf(fabsf(v.x), fabsf(v.y)),
                           fmaxf(fabsf(v.z), fabsf(v.w))));
    }
    #pragma unroll
    for (int off = 32; off; off >>= 1) m = fmaxf(m, __shfl_down(m, off));
    __shared__ float red[4];
    int lane = threadIdx.x & 63, wv = threadIdx.x >> 6;
    if (lane == 0) red[wv] = m;
    __syncthreads();
    if (threadIdx.x == 0) {
        m = fmaxf(fmaxf(red[0], red[1]), fmaxf(red[2], red[3]));
        atomicMax(slot, __float_as_uint(m));
    }
}

// ---------- quantize: blocks [0,1792) -> x, [1792,2080) -> w ----------
// qx: per (b,h) row of 7424 B: byte = c*928 + s*16 + j; slot s in [1,56] holds
//     pixel w = s-1, ci = c*16+j; slots 0 and 57 zero.
// qw3: byte = g*73728 + k*2048 + mi*1024 + jh*512 + co31*16 + jl
//   co = g*64 + mi*32 + co31, k = (kh*3+kw)*4 + cc, ci = cc*32 + jh*16 + jl.
__global__ __launch_bounds__(256) void quant_all_kernel(const float* __restrict__ x,
                                                        const float* __restrict__ w,
                                                        signed char* __restrict__ qx,
                                                        int* __restrict__ qw,
                                                        const unsigned* __restrict__ mbits) {
    if (blockIdx.x < NBLK_QX) {
        __shared__ signed char tile[WW * 132];
        const int bh = blockIdx.x;
        const int b = bh / HH, h = bh % HH;
        const float s = __uint_as_float(mbits[0]) / QDIV;
        const float* src = x + (size_t)b * (CIN * HH * WW) + (size_t)h * WW;
        #pragma unroll
        for (int i = 0; i < 7; ++i) {                 // 128 ci * 14 float4 = 1792
            int e = threadIdx.x + i * 256;
            int ci = e / 14, wq = e - ci * 14;
            float4 v = *(const float4*)(src + (size_t)ci * (HH * WW) + wq * 4);
            float qa = fminf(fmaxf(rintf(v.x / s), -8.f), 7.f);
            float qb = fminf(fmaxf(rintf(v.y / s), -8.f), 7.f);
            float qc = fminf(fmaxf(rintf(v.z / s), -8.f), 7.f);
            float qd = fminf(fmaxf(rintf(v.w / s), -8.f), 7.f);
            signed char* tp = &tile[(wq * 4) * 132 + ci];
            tp[0]   = (signed char)qa;
            tp[132] = (signed char)qb;
            tp[264] = (signed char)qc;
            tp[396] = (signed char)qd;
        }
        __syncthreads();
        int* dst = (int*)(qx + (size_t)bh * ROWB);
        for (int d = threadIdx.x; d < ROWB / 4; d += 256) {   // 1856 dwords
            int u = d >> 2, dw = d & 3;
            int c = u / NSLOT, s2 = u - c * NSLOT;
            int v = 0;
            if (s2 >= 1 && s2 <= WW)
                v = *(const int*)&tile[(s2 - 1) * 132 + c * 16 + dw * 4];
            dst[d] = v;
        }
    } else {
        int d = (blockIdx.x - NBLK_QX) * 256 + threadIdx.x;  // 73728 dwords
        int g  = d / 18432;
        int r1 = d - g * 18432;
        int k  = r1 >> 9;
        int q9 = r1 & 511;
        int mi = q9 >> 8;
        int u2 = q9 & 255;
        int jh = u2 >> 7;
        int co31 = (u2 >> 2) & 31;
        int jl4  = u2 & 3;
        int co = g * 64 + mi * 32 + co31;
        int t = k >> 2, cc = k & 3;
        int kh = t / 3, kw = t - kh * 3;
        float s = __uint_as_float(mbits[1]) / QDIV;
        int pack = 0;
        #pragma unroll
        for (int j = 0; j < 4; ++j) {
            int ci = cc * 32 + jh * 16 + jl4 * 4 + j;
            float v = w[(((size_t)co * CIN + ci) * 3 + kh) * 3 + kw];
            float q = fminf(fmaxf(rintf(v / s), -8.f), 7.f);
            pack |= (((int)q) & 0xFF) << (8 * j);
        }
        qw[d] = pack;
    }
}

// ---------- conv: i8-MFMA, 3 blocks/CU, fine-grained weight dbuf ----------
// Block: 256 thr / 4 waves; 64 co (group g) x 4 output rows; wave = 64co x 56px,
// acc[2][2]. LDS: x rows h0-1..h0+4 (44.5 KB) + weight dbuf 2x4KB = 52.7 KB
// -> 3 blocks/CU (12 waves/CU, 3/SIMD). K-loop: 18 segments x 2 chunks of pure
// ds_read+MFMA; 1 staging load/thread/segment; barriers overlap across blocks.
__global__ __launch_bounds__(256, 3) void conv_mfma_kernel(
        const signed char* __restrict__ qx,
        const signed char* __restrict__ qxzero,
        const signed char* __restrict__ qw3,
        const unsigned* __restrict__ mbits,
        const float* __restrict__ bias,
        float* __restrict__ out) {
    __shared__ signed char lds[LDS_TOTAL];
    signed char* xlds = lds;
    signed char* wlds = lds + XLDS_BYTES;

    // XCD-chunked swizzle (1792 % 8 == 0 -> bijective); g fastest in a chunk
    const int sbid = (blockIdx.x & 7) * 224 + (blockIdx.x >> 3);
    const int g    = sbid & 3;
    const int brg  = sbid >> 2;       // 0..447
    const int rg   = brg % 14;
    const int b    = brg / 14;
    const int h0   = rg * 4;

    const int tid    = threadIdx.x;
    const int rowidx = tid >> 6;      // wave id = output row 0..3
    const int lane   = tid & 63;
    const int l31    = tid & 31;
    const int lhalf  = (tid >> 5) & 1;

    const signed char* wgrp = qw3 + (size_t)g * WGRP;

    // ---- prologue: weight segment 0 (4KB) + x rows h0-1..h0+4 (2784 units) ----
    load_lds16(wgrp + tid * 16, wlds + tid * 16);
    const signed char* qxb = qx + (size_t)(b * HH) * ROWB;
    #pragma unroll
    for (int i = 0; i < 11; ++i) {
        const int u = tid + i * 256;
        if (u < 2784) {
            const int r = u / 464, c = u - r * 464;
            const int hy = h0 - 1 + r;
            const signed char* src = (hy >= 0 && hy < HH) ? qxb + hy * ROWB + c * 16
                                                          : qxzero + c * 16;
            load_lds16(src, xlds + u * 16);
        }
    }
    __syncthreads();

    v16i acc[2][2];
    #pragma unroll
    for (int mi = 0; mi < 2; ++mi)
        #pragma unroll
        for (int ni = 0; ni < 2; ++ni)
            #pragma unroll
            for (int r = 0; r < 16; ++r) acc[mi][ni][r] = 0;

    #pragma unroll
    for (int s = 0; s < 18; ++s) {
        if (s < 17)   // stage next 2-chunk segment: one 16B load per thread
            load_lds16(wgrp + (s + 1) * WSEG + tid * 16,
                       wlds + ((s + 1) & 1) * WSEG + tid * 16);

        const signed char* wseg = wlds + (s & 1) * WSEG + lane * 16;
        #pragma unroll
        for (int j = 0; j < 2; ++j) {
            const int K = s * 2 + j;
            const int t = K >> 2, cc = K & 3;
            const int kh = t / 3, kw = t - kh * 3;
            const v4i a0 = *(const v4i*)(wseg + j * 2048);
            const v4i a1 = *(const v4i*)(wseg + j * 2048 + 1024);
            const signed char* xp = xlds + (rowidx + kh) * ROWB
                                    + (cc * 2 + lhalf) * CSTRIDE + (l31 + kw) * 16;
            const v4i b0 = *(const v4i*)xp;
            const v4i b1 = *(const v4i*)(xp + 512);
            acc[0][0] = __builtin_amdgcn_mfma_i32_32x32x32_i8(a0, b0, acc[0][0], 0, 0, 0);
            acc[1][0] = __builtin_amdgcn_mfma_i32_32x32x32_i8(a1, b0, acc[1][0], 0, 0, 0);
            acc[0][1] = __builtin_amdgcn_mfma_i32_32x32x32_i8(a0, b1, acc[0][1], 0, 0, 0);
            acc[1][1] = __builtin_amdgcn_mfma_i32_32x32x32_i8(a1, b1, acc[1][1], 0, 0, 0);
        }
        if (s < 17) __syncthreads();   // publish next buffer; overlaps across 3 blocks/CU
    }

    // ---- epilogue: dequant + bias ----
    const float s = (__uint_as_float(mbits[0]) / QDIV) *
                    (__uint_as_float(mbits[1]) / QDIV);
    const int hrow = h0 + rowidx;
    #pragma unroll
    for (int mi = 0; mi < 2; ++mi) {
        #pragma unroll
        for (int r = 0; r < 16; ++r) {
            const int co = g * 64 + mi * 32 + (r & 3) + 8 * (r >> 2) + 4 * lhalf;
            const float bv = bias[co];
            float* orow = out + ((size_t)(b * COUT + co) * HH + hrow) * WW;
            orow[l31] = (float)acc[mi][0][r] * s + bv;
            if (l31 < WW - 32) orow[32 + l31] = (float)acc[mi][1][r] * s + bv;
        }
    }
}

extern "C" void kernel_launch(void* const* d_in, const int* in_sizes, int n_in,
                              void* d_out, int out_size, void* d_ws, size_t ws_size,
                              hipStream_t stream) {
    const float* x    = (const float*)d_in[0];
    const float* w    = (const float*)d_in[1];
    const float* bias = (const float*)d_in[2];
    float* out = (float*)d_out;

    unsigned* mbits = (unsigned*)d_ws;
    signed char* qxzero = (signed char*)d_ws + 256;
    signed char* qx     = qxzero + ROWB;
    signed char* qw3    = qx + (size_t)B_ * HH * ROWB;

    hipMemsetAsync(d_ws, 0, 256 + ROWB, stream);   // mbits + qxzero in one shot
    hipLaunchKernelGGL(absmax_all_kernel, dim3(NBLK_AX + NBLK_AW), dim3(256), 0, stream,
                       x, w, mbits);
    hipLaunchKernelGGL(quant_all_kernel, dim3(NBLK_QX + NBLK_QW), dim3(256), 0, stream,
                       x, w, qx, (int*)qw3, mbits);
    hipLaunchKernelGGL(conv_mfma_kernel, dim3(B_ * 14 * 4), dim3(256), 0, stream,
                       qx, qxzero, qw3, mbits, bias, out);
}